// Round 8
// baseline (124.512 us; speedup 1.0000x reference)
//
#include <hip/hip_runtime.h>
#include <hip/hip_bf16.h>

typedef float  f32x4  __attribute__((ext_vector_type(4)));
typedef __bf16 bf16x8 __attribute__((ext_vector_type(8)));
typedef unsigned int   u32;
typedef unsigned short u16;
typedef u32   u32x2  __attribute__((ext_vector_type(2)));
typedef u32   u32x4  __attribute__((ext_vector_type(4)));
typedef u16   u16x4  __attribute__((ext_vector_type(4)));
typedef u16   u16x8  __attribute__((ext_vector_type(8)));

#define DEV __device__ __forceinline__

constexpr int NB = 8, T = 2048, C = 1024, H = 128;
constexpr int BT = NB * T;

union Frag {
  bf16x8 v;
  u32x4  u4;
  u32x2  u2[2];
  u32    u[4];
  u16    s[8];
};

DEV u16 f2bu(float f) {
  __hip_bfloat16 h = __float2bfloat16(f);
  return __builtin_bit_cast(u16, h);
}
DEV float bu2f(u16 u) {
  return __bfloat162float(__builtin_bit_cast(__hip_bfloat16, u));
}
DEV f32x4 MFMA(bf16x8 a, bf16x8 b, f32x4 c) {
  return __builtin_amdgcn_mfma_f32_16x16x32_bf16(a, b, c, 0, 0, 0);
}

// ---------------------------------------------------------------------------
// Lane-contiguous fragment layouts (16B/lane, 1KB/wave per load):
//   wpq/wpk: [tt8][kc32][hl2][lane64][e8]        (tile-kc stride 1024 u16)
//   wpv:     [tt8][kc32][lane64][e8]             (512)
//   qpk/kpk: [b8][tile128][hs4][hl2][lane64][e8] (tile stride 4096)
//   vpk:     [b8][kt64][ht8][lane64][e8]         (kt stride 4096)
// ---------------------------------------------------------------------------

__global__ void prep_w(const float* __restrict__ Wk, const float* __restrict__ Wq,
                       const float* __restrict__ Wv,
                       u16* __restrict__ wpq, u16* __restrict__ wpk,
                       u16* __restrict__ wpv) {
  const int id = blockIdx.x * 256 + threadIdx.x;   // 24*32*64 = 49152
  if (id >= 24 * 32 * 64) return;
  const int lane = id & 63;
  const int kc   = (id >> 6) & 31;
  const int tile = id >> 11;          // 0..23
  const int mat  = tile >> 3;         // 0=q 1=k 2=v
  const int tt   = tile & 7;
  const int n    = tt * 16 + (lane & 15);
  const float* W = (mat == 0) ? Wq : (mat == 1) ? Wk : Wv;
  u16x8 hi, lo;
  #pragma unroll
  for (int e = 0; e < 8; ++e) {
    const int k = kc * 32 + 4 * (lane >> 4) + (e & 3) + 16 * (e >> 2);
    const float w = W[(size_t)k * H + n];
    u16 h = f2bu(w);
    hi[e] = h;
    lo[e] = f2bu(w - bu2f(h));
  }
  if (mat == 2) {
    *(u16x8*)(wpv + ((size_t)(tt * 32 + kc) * 64 + lane) * 8) = hi;
  } else {
    u16* p = ((mat == 0) ? wpq : wpk) +
             (((size_t)(tt * 32 + kc) * 2 + 0) * 64 + lane) * 8;
    *(u16x8*)p         = hi;
    *(u16x8*)(p + 512) = lo;
  }
}

// ---------------------------------------------------------------------------
// Kernel 1: projections v4 — single-barrier double-buffered pipeline.
// BM=64, 4 waves; wave w owns rows 16w..16w+15 x 6 n-tiles (2q+2k+2v of
// n-group ng). Per K-step: issue next-tile global loads EARLY, compute from
// buf[cur], write staged regs to buf[cur^1], ONE barrier. bid = mt*4+ng so
// the 4 blocks sharing an x-tile land on the same XCD (256 % 8 == 0).
// LDS 76KB -> 2 blocks/CU.
// ---------------------------------------------------------------------------
__global__ __launch_bounds__(256, 2) void proj_kernel(
    const float* __restrict__ x,
    const u16* __restrict__ wpq, const u16* __restrict__ wpk,
    const u16* __restrict__ wpv,
    u16* __restrict__ qpk, u16* __restrict__ kpk, u16* __restrict__ vpk) {
  __shared__ u16 xh[2][64][72];        // 18.4 KB
  __shared__ u16 xl[2][64][72];        // 18.4 KB
  __shared__ u16 wsl[2][1280 * 8];     // 40 KB: [kcg2][plane10][lane64][e8]
  const int tid  = threadIdx.x;
  const int mt   = blockIdx.x >> 2;        // 0..255
  const int ng   = blockIdx.x & 3;         // 0..3
  const int m0   = mt * 64;
  const int w    = tid >> 6;               // 0..3
  const int lane = tid & 63;
  const int lg   = lane >> 4, lc = lane & 15;

  const int lrow = tid >> 2;               // 0..63
  const int lcs  = (tid & 3) * 16;         // 0,16,32,48

  f32x4 zero = {0.f, 0.f, 0.f, 0.f};
  f32x4 acc[6];                            // q0,q1,k0,k1,v0,v1
  #pragma unroll
  for (int j = 0; j < 6; ++j) acc[j] = zero;

  f32x4 xv[4];
  u16x8 wreg[5];

  auto stage_load = [&](int ks) {
    #pragma unroll
    for (int j = 0; j < 4; ++j)
      xv[j] = *(const f32x4*)&x[(size_t)(m0 + lrow) * C + ks * 64 + lcs + 4 * j];
    #pragma unroll
    for (int i = 0; i < 5; ++i) {
      const int c = tid + 256 * i;         // 0..1279
      const int kcg   = c >= 640;
      const int rem   = c - kcg * 640;
      const int plane = rem >> 6;
      const int ln    = rem & 63;
      const int kabs  = ks * 2 + kcg;
      const u16* src;
      if (plane < 4)
        src = wpq + (size_t)((2 * ng + (plane >> 1)) * 32 + kabs) * 1024 +
              (plane & 1) * 512 + ln * 8;
      else if (plane < 8)
        src = wpk + (size_t)((2 * ng + ((plane - 4) >> 1)) * 32 + kabs) * 1024 +
              ((plane - 4) & 1) * 512 + ln * 8;
      else
        src = wpv + (size_t)((2 * ng + (plane - 8)) * 32 + kabs) * 512 + ln * 8;
      wreg[i] = *(const u16x8*)src;
    }
  };

  auto stage_write = [&](int buf) {
    #pragma unroll
    for (int j = 0; j < 4; ++j) {
      u16x4 hv, lv;
      #pragma unroll
      for (int e = 0; e < 4; ++e) {
        u16 h = f2bu(xv[j][e]);
        hv[e] = h;
        lv[e] = f2bu(xv[j][e] - bu2f(h));
      }
      *(u16x4*)&xh[buf][lrow][lcs + 4 * j] = hv;
      *(u16x4*)&xl[buf][lrow][lcs + 4 * j] = lv;
    }
    #pragma unroll
    for (int i = 0; i < 5; ++i)
      *(u16x8*)&wsl[buf][(size_t)(tid + 256 * i) * 8] = wreg[i];
  };

  auto compute = [&](int buf) {
    #pragma unroll
    for (int kc = 0; kc < 2; ++kc) {
      Frag axh, axl;
      const int row = 16 * w + lc;
      axh.u2[0] = *(const u32x2*)&xh[buf][row][kc * 32 + 4 * lg];
      axh.u2[1] = *(const u32x2*)&xh[buf][row][kc * 32 + 16 + 4 * lg];
      axl.u2[0] = *(const u32x2*)&xl[buf][row][kc * 32 + 4 * lg];
      axl.u2[1] = *(const u32x2*)&xl[buf][row][kc * 32 + 16 + 4 * lg];
      #pragma unroll
      for (int jt = 0; jt < 2; ++jt) {
        {
          Frag bh, bl;
          bh.u4 = *(const u32x4*)&wsl[buf][((size_t)(kc * 10 + jt * 2 + 0) * 64 + lane) * 8];
          bl.u4 = *(const u32x4*)&wsl[buf][((size_t)(kc * 10 + jt * 2 + 1) * 64 + lane) * 8];
          acc[jt] = MFMA(axh.v, bh.v, acc[jt]);
          acc[jt] = MFMA(axh.v, bl.v, acc[jt]);
          acc[jt] = MFMA(axl.v, bh.v, acc[jt]);
        }
        {
          Frag bh, bl;
          bh.u4 = *(const u32x4*)&wsl[buf][((size_t)(kc * 10 + 4 + jt * 2 + 0) * 64 + lane) * 8];
          bl.u4 = *(const u32x4*)&wsl[buf][((size_t)(kc * 10 + 4 + jt * 2 + 1) * 64 + lane) * 8];
          acc[2 + jt] = MFMA(axh.v, bh.v, acc[2 + jt]);
          acc[2 + jt] = MFMA(axh.v, bl.v, acc[2 + jt]);
          acc[2 + jt] = MFMA(axl.v, bh.v, acc[2 + jt]);
        }
        {
          Frag bh;
          bh.u4 = *(const u32x4*)&wsl[buf][((size_t)(kc * 10 + 8 + jt) * 64 + lane) * 8];
          acc[4 + jt] = MFMA(axh.v, bh.v, acc[4 + jt]);
        }
      }
    }
  };

  // prologue
  stage_load(0);
  stage_write(0);
  __syncthreads();
  int cur = 0;
  for (int ks = 0; ks < 16; ++ks) {
    if (ks < 15) stage_load(ks + 1);       // issue early (async under compute)
    compute(cur);
    if (ks < 15) stage_write(cur ^ 1);     // other buffer: no WAR hazard
    __syncthreads();                       // single barrier per K-step
    cur ^= 1;
  }

  // Epilogue: value = Out[m0 + 16w + 4lg + r][(2ng+jt)*16 + lc]
  const int tb_abs = mt * 4 + w;
  const int b  = tb_abs >> 7;
  const int tb = tb_abs & 127;
  #pragma unroll
  for (int j = 0; j < 6; ++j) {
    const int mat = j >> 1;
    const int jt  = j & 1;
    const int tt  = 2 * ng + jt;
    #pragma unroll
    for (int r = 0; r < 4; ++r) {
      const float val = acc[j][r];
      if (mat < 2) {
        const u16 hvv = f2bu(val);
        const u16 lvv = f2bu(val - bu2f(hvv));
        const int lane_c = 4 * lg + r + 16 * (lc >> 2);
        const int hs = tt >> 1;
        const int e  = (lc & 3) + 4 * (tt & 1);
        u16* dst = ((mat == 0) ? qpk : kpk) +
                   (((size_t)(b * 128 + tb) * 4 + hs) * 2 * 64 + lane_c) * 8 + e;
        dst[0]   = hvv;
        dst[512] = lvv;
      } else {
        const int kt = tb >> 1;
        const int lane_c = lc + 16 * lg;
        const int e = r + 4 * (tb & 1);
        vpk[(((size_t)(b * 64 + kt) * 8 + tt) * 64 + lane_c) * 8 + e] = f2bu(val);
      }
    }
  }
}

// ---------------------------------------------------------------------------
// Kernel 2: causal flash attention (round-4 structure + setprio on MFMA
// clusters). 8 waves, intra-block split-K (kb = w mod 8), 1 q-tile/wave.
// Swapped QK^T so P lands in PV's A-operand layout. LDS combine (bf16).
// ---------------------------------------------------------------------------
__global__ __launch_bounds__(512, 4) void attn_kernel(
    const u16* __restrict__ qpk, const u16* __restrict__ kpk,
    const u16* __restrict__ vpk, float* __restrict__ out) {
  __shared__ float lm[8][16];
  __shared__ float ll[8][16];
  __shared__ u16 lo[8][16][132];     // bf16 partial O

  const int bid = blockIdx.x;
  const int b   = bid & 7;           // batch -> XCD affinity
  const int qt  = bid >> 3;          // 0..127
  const int w    = threadIdx.x >> 6;
  const int lane = threadIdx.x & 63;
  const int lg = lane >> 4, lc = lane & 15;

  // Q fragments: [b][qt][hs][hl][lane][8], tile stride 4096 u16
  Frag bqh[4], bql[4];
  const u16* qp = qpk + (size_t)(b * 128 + qt) * 4096 + lane * 8;
  #pragma unroll
  for (int hs = 0; hs < 4; ++hs) {
    bqh[hs].u4 = *(const u32x4*)(qp + (size_t)(hs * 2 + 0) * 512);
    bql[hs].u4 = *(const u32x4*)(qp + (size_t)(hs * 2 + 1) * 512);
  }

  f32x4 zero = {0.f, 0.f, 0.f, 0.f};
  f32x4 o_acc[8];
  #pragma unroll
  for (int i = 0; i < 8; ++i) o_acc[i] = zero;
  float m_run = -INFINITY, l_run = 0.f;

  const int myq = qt * 16 + lc;
  const int nkb = qt >> 2;           // last 64-wide k-block

  for (int kb = w; kb <= nkb; kb += 8) {
    f32x4 s[4];
    #pragma unroll
    for (int t = 0; t < 4; ++t) s[t] = zero;

    const u16* kp = kpk + (size_t)(b * 128 + kb * 4) * 4096 + lane * 8;
    __builtin_amdgcn_s_setprio(1);
    #pragma unroll
    for (int t = 0; t < 4; ++t) {
      #pragma unroll
      for (int hs = 0; hs < 4; ++hs) {
        const u16* p = kp + (size_t)(t * 8 + hs * 2) * 512;
        Frag akh, akl;
        akh.u4 = *(const u32x4*)p;
        akl.u4 = *(const u32x4*)(p + 512);
        s[t] = MFMA(akh.v, bqh[hs].v, s[t]);
        s[t] = MFMA(akh.v, bql[hs].v, s[t]);
        s[t] = MFMA(akl.v, bqh[hs].v, s[t]);
      }
    }
    __builtin_amdgcn_s_setprio(0);

    // scale by sqrt(C)=32; causal + (tril==0 -> -inf) semantics
    float pmax = -INFINITY;
    #pragma unroll
    for (int t = 0; t < 4; ++t) {
      #pragma unroll
      for (int r = 0; r < 4; ++r) {
        const int kk = kb * 64 + t * 16 + 4 * lg + r;
        float v = s[t][r] * 32.0f;
        if (kk > myq || v == 0.0f) v = -INFINITY;
        s[t][r] = v;
        pmax = fmaxf(pmax, v);
      }
    }
    pmax = fmaxf(pmax, __shfl_xor(pmax, 16));
    pmax = fmaxf(pmax, __shfl_xor(pmax, 32));
    const float m_new = fmaxf(m_run, pmax);
    const float alpha = __expf(m_run - m_new);

    float sum = 0.f;
    u16 pb[16];
    #pragma unroll
    for (int t = 0; t < 4; ++t) {
      #pragma unroll
      for (int r = 0; r < 4; ++r) {
        const float p = __expf(s[t][r] - m_new);
        sum += p;
        pb[t * 4 + r] = f2bu(p);
      }
    }
    sum += __shfl_xor(sum, 16);
    sum += __shfl_xor(sum, 32);
    l_run = l_run * alpha + sum;
    m_run = m_new;

    float al[4];
    #pragma unroll
    for (int r = 0; r < 4; ++r) al[r] = __shfl(alpha, 4 * lg + r);
    #pragma unroll
    for (int i = 0; i < 8; ++i) {
      #pragma unroll
      for (int r = 0; r < 4; ++r) o_acc[i][r] *= al[r];
    }

    Frag pa[2];
    #pragma unroll
    for (int ks = 0; ks < 2; ++ks) {
      #pragma unroll
      for (int e = 0; e < 8; ++e)
        pa[ks].s[e] = pb[(2 * ks + (e >> 2)) * 4 + (e & 3)];
    }

    __builtin_amdgcn_s_setprio(1);
    #pragma unroll
    for (int ks = 0; ks < 2; ++ks) {
      const u16* vp = vpk + (size_t)(b * 64 + kb * 2 + ks) * 4096 + lane * 8;
      #pragma unroll
      for (int ht = 0; ht < 8; ++ht) {
        Frag bv;
        bv.u4 = *(const u32x4*)(vp + (size_t)ht * 512);
        o_acc[ht] = MFMA(pa[ks].v, bv.v, o_acc[ht]);
      }
    }
    __builtin_amdgcn_s_setprio(0);
  }

  // --- combine 8 partials through LDS ---
  if (lane < 16) { lm[w][lane] = m_run; ll[w][lane] = l_run; }
  #pragma unroll
  for (int ht = 0; ht < 8; ++ht)
    #pragma unroll
    for (int r = 0; r < 4; ++r)
      lo[w][4 * lg + r][ht * 16 + lc] = f2bu(o_acc[ht][r]);
  __syncthreads();

  const int tid = threadIdx.x;
  const int q  = tid >> 5;            // 0..15
  const int hb = (tid & 31) * 4;      // 0..124
  float M = -INFINITY;
  #pragma unroll
  for (int ww = 0; ww < 8; ++ww) M = fmaxf(M, lm[ww][q]);
  float lsum = 0.f;
  f32x4 osum = {0.f, 0.f, 0.f, 0.f};
  #pragma unroll
  for (int ww = 0; ww < 8; ++ww) {
    const float sc = __expf(lm[ww][q] - M);
    lsum += sc * ll[ww][q];
    const u16x4 ov = *(const u16x4*)&lo[ww][q][hb];
    #pragma unroll
    for (int j = 0; j < 4; ++j) osum[j] += sc * bu2f(ov[j]);
  }
  const float inv = 1.0f / lsum;
  f32x4 res = {osum[0] * inv, osum[1] * inv, osum[2] * inv, osum[3] * inv};
  *(f32x4*)&out[((size_t)(b * T + qt * 16 + q)) * H + hb] = res;
}

// ---------------------------------------------------------------------------
extern "C" void kernel_launch(void* const* d_in, const int* in_sizes, int n_in,
                              void* d_out, int out_size, void* d_ws, size_t ws_size,
                              hipStream_t stream) {
  (void)in_sizes; (void)n_in; (void)out_size; (void)ws_size;
  const float* x  = (const float*)d_in[0];
  const float* Wk = (const float*)d_in[1];
  const float* Wq = (const float*)d_in[2];
  const float* Wv = (const float*)d_in[3];
  float* out = (float*)d_out;

  u16* w = (u16*)d_ws;
  const size_t WPQK = (size_t)8 * 32 * 2 * 64 * 8;       // 262144
  const size_t WPV  = (size_t)8 * 32 * 64 * 8;           // 131072
  const size_t QKP  = (size_t)NB * 128 * 4 * 2 * 64 * 8; // 4194304
  u16* wpq = w;
  u16* wpk = wpq + WPQK;
  u16* wpv = wpk + WPQK;
  u16* qpk = wpv + WPV;
  u16* kpk = qpk + QKP;
  u16* vpk = kpk + QKP;

  prep_w<<<192, 256, 0, stream>>>(Wk, Wq, Wv, wpq, wpk, wpv);
  proj_kernel<<<1024, 256, 0, stream>>>(x, wpq, wpk, wpv, qpk, kpk, vpk);
  attn_kernel<<<NB * (T / 16), 512, 0, stream>>>(qpk, kpk, vpk, out);
}

// Round 9
// 103.293 us; speedup vs baseline: 1.2054x; 1.2054x over previous
//
#include <hip/hip_runtime.h>
#include <hip/hip_bf16.h>

typedef float  f32x4  __attribute__((ext_vector_type(4)));
typedef __bf16 bf16x8 __attribute__((ext_vector_type(8)));
typedef unsigned int   u32;
typedef unsigned short u16;
typedef u32   u32x2  __attribute__((ext_vector_type(2)));
typedef u32   u32x4  __attribute__((ext_vector_type(4)));
typedef u16   u16x4  __attribute__((ext_vector_type(4)));
typedef u16   u16x8  __attribute__((ext_vector_type(8)));

#define DEV __device__ __forceinline__

constexpr int NB = 8, T = 2048, C = 1024, H = 128;
constexpr int BT = NB * T;

union Frag {
  bf16x8 v;
  u32x4  u4;
  u32x2  u2[2];
  u32    u[4];
  u16    s[8];
};

DEV u16 f2bu(float f) {
  __hip_bfloat16 h = __float2bfloat16(f);
  return __builtin_bit_cast(u16, h);
}
DEV float bu2f(u16 u) {
  return __bfloat162float(__builtin_bit_cast(__hip_bfloat16, u));
}
DEV f32x4 MFMA(bf16x8 a, bf16x8 b, f32x4 c) {
  return __builtin_amdgcn_mfma_f32_16x16x32_bf16(a, b, c, 0, 0, 0);
}

// ---------------------------------------------------------------------------
// Lane-contiguous fragment layouts (16B/lane, 1KB/wave per load):
//   wpq/wpk: [tt8][kc32][hl2][lane64][e8]        (tile-kc stride 1024 u16)
//   wpv:     [tt8][kc32][lane64][e8]             (512)
//   qpk/kpk: [b8][tile128][hs4][hl2][lane64][e8] (tile stride 4096)
//   vpk:     [b8][kt64][ht8][lane64][e8]         (kt stride 4096)
// ---------------------------------------------------------------------------

__global__ void prep_w(const float* __restrict__ Wk, const float* __restrict__ Wq,
                       const float* __restrict__ Wv,
                       u16* __restrict__ wpq, u16* __restrict__ wpk,
                       u16* __restrict__ wpv) {
  const int id = blockIdx.x * 256 + threadIdx.x;   // 24*32*64 = 49152
  if (id >= 24 * 32 * 64) return;
  const int lane = id & 63;
  const int kc   = (id >> 6) & 31;
  const int tile = id >> 11;          // 0..23
  const int mat  = tile >> 3;         // 0=q 1=k 2=v
  const int tt   = tile & 7;
  const int n    = tt * 16 + (lane & 15);
  const float* W = (mat == 0) ? Wq : (mat == 1) ? Wk : Wv;
  u16x8 hi, lo;
  #pragma unroll
  for (int e = 0; e < 8; ++e) {
    const int k = kc * 32 + 4 * (lane >> 4) + (e & 3) + 16 * (e >> 2);
    const float w = W[(size_t)k * H + n];
    u16 h = f2bu(w);
    hi[e] = h;
    lo[e] = f2bu(w - bu2f(h));
  }
  if (mat == 2) {
    *(u16x8*)(wpv + ((size_t)(tt * 32 + kc) * 64 + lane) * 8) = hi;
  } else {
    u16* p = ((mat == 0) ? wpq : wpk) +
             (((size_t)(tt * 32 + kc) * 2 + 0) * 64 + lane) * 8;
    *(u16x8*)p         = hi;
    *(u16x8*)(p + 512) = lo;
  }
}

// ---------------------------------------------------------------------------
// Kernel 1: projections v5 — single-barrier double-buffered pipeline,
// ng-MAJOR grid (bid = ng*256 + mt; 256%8==0 so the 4 blocks sharing an
// x-tile land on the SAME XCD -> x re-reads are L2 hits, not HBM).
// Per K-step: issue next-tile global loads EARLY (latency hides under 28
// MFMAs), compute from buf[cur], write staged regs to buf[cur^1], ONE
// barrier. Staging addresses hoisted (ks-invariant per thread).
// ---------------------------------------------------------------------------
__global__ __launch_bounds__(256, 2) void proj_kernel(
    const float* __restrict__ x,
    const u16* __restrict__ wpq, const u16* __restrict__ wpk,
    const u16* __restrict__ wpv,
    u16* __restrict__ qpk, u16* __restrict__ kpk, u16* __restrict__ vpk) {
  __shared__ u16 xh[2][64][72];        // 18.4 KB
  __shared__ u16 xl[2][64][72];        // 18.4 KB
  __shared__ u16 wsl[2][1280 * 8];     // 40 KB: [kcg2][plane10][lane64][e8]
  const int tid  = threadIdx.x;
  const int ng   = blockIdx.x >> 8;        // 0..3  (ng-major!)
  const int mt   = blockIdx.x & 255;       // 0..255
  const int m0   = mt * 64;
  const int w    = tid >> 6;               // 0..3
  const int lane = tid & 63;
  const int lg   = lane >> 4, lc = lane & 15;

  const int lrow = tid >> 2;               // 0..63
  const int lcs  = (tid & 3) * 16;         // 0,16,32,48

  // hoisted per-thread staging sources (ks-invariant)
  const float* xsrc = x + (size_t)(m0 + lrow) * C + lcs;
  const u16* wbase[5];
  int wstep[5];
  #pragma unroll
  for (int i = 0; i < 5; ++i) {
    const int c = tid + 256 * i;           // 0..1279
    const int kcg   = c >= 640;
    const int rem   = c - kcg * 640;
    const int plane = rem >> 6;
    const int ln    = rem & 63;
    const u16* base;
    int stride;
    if (plane < 4) {
      base = wpq + (size_t)((2 * ng + (plane >> 1)) * 32) * 1024 +
             (plane & 1) * 512 + ln * 8;
      stride = 1024;
    } else if (plane < 8) {
      const int p = plane - 4;
      base = wpk + (size_t)((2 * ng + (p >> 1)) * 32) * 1024 +
             (p & 1) * 512 + ln * 8;
      stride = 1024;
    } else {
      base = wpv + (size_t)((2 * ng + (plane - 8)) * 32) * 512 + ln * 8;
      stride = 512;
    }
    wbase[i] = base + kcg * stride;
    wstep[i] = 2 * stride;
  }

  f32x4 zero = {0.f, 0.f, 0.f, 0.f};
  f32x4 acc[6];                            // q0,q1,k0,k1,v0,v1
  #pragma unroll
  for (int j = 0; j < 6; ++j) acc[j] = zero;

  f32x4 xv[4];
  u16x8 wreg[5];

  auto stage_load = [&](int ks) {
    #pragma unroll
    for (int j = 0; j < 4; ++j)
      xv[j] = *(const f32x4*)(xsrc + ks * 64 + 4 * j);
    #pragma unroll
    for (int i = 0; i < 5; ++i)
      wreg[i] = *(const u16x8*)(wbase[i] + (size_t)ks * wstep[i]);
  };

  auto stage_write = [&](int buf) {
    #pragma unroll
    for (int j = 0; j < 4; ++j) {
      u16x4 hv, lv;
      #pragma unroll
      for (int e = 0; e < 4; ++e) {
        u16 h = f2bu(xv[j][e]);
        hv[e] = h;
        lv[e] = f2bu(xv[j][e] - bu2f(h));
      }
      *(u16x4*)&xh[buf][lrow][lcs + 4 * j] = hv;
      *(u16x4*)&xl[buf][lrow][lcs + 4 * j] = lv;
    }
    #pragma unroll
    for (int i = 0; i < 5; ++i)
      *(u16x8*)&wsl[buf][(size_t)(tid + 256 * i) * 8] = wreg[i];
  };

  auto compute = [&](int buf) {
    #pragma unroll
    for (int kc = 0; kc < 2; ++kc) {
      Frag axh, axl;
      const int row = 16 * w + lc;
      axh.u2[0] = *(const u32x2*)&xh[buf][row][kc * 32 + 4 * lg];
      axh.u2[1] = *(const u32x2*)&xh[buf][row][kc * 32 + 16 + 4 * lg];
      axl.u2[0] = *(const u32x2*)&xl[buf][row][kc * 32 + 4 * lg];
      axl.u2[1] = *(const u32x2*)&xl[buf][row][kc * 32 + 16 + 4 * lg];
      #pragma unroll
      for (int jt = 0; jt < 2; ++jt) {
        {
          Frag bh, bl;
          bh.u4 = *(const u32x4*)&wsl[buf][((size_t)(kc * 10 + jt * 2 + 0) * 64 + lane) * 8];
          bl.u4 = *(const u32x4*)&wsl[buf][((size_t)(kc * 10 + jt * 2 + 1) * 64 + lane) * 8];
          acc[jt] = MFMA(axh.v, bh.v, acc[jt]);
          acc[jt] = MFMA(axh.v, bl.v, acc[jt]);
          acc[jt] = MFMA(axl.v, bh.v, acc[jt]);
        }
        {
          Frag bh, bl;
          bh.u4 = *(const u32x4*)&wsl[buf][((size_t)(kc * 10 + 4 + jt * 2 + 0) * 64 + lane) * 8];
          bl.u4 = *(const u32x4*)&wsl[buf][((size_t)(kc * 10 + 4 + jt * 2 + 1) * 64 + lane) * 8];
          acc[2 + jt] = MFMA(axh.v, bh.v, acc[2 + jt]);
          acc[2 + jt] = MFMA(axh.v, bl.v, acc[2 + jt]);
          acc[2 + jt] = MFMA(axl.v, bh.v, acc[2 + jt]);
        }
        {
          Frag bh;
          bh.u4 = *(const u32x4*)&wsl[buf][((size_t)(kc * 10 + 8 + jt) * 64 + lane) * 8];
          acc[4 + jt] = MFMA(axh.v, bh.v, acc[4 + jt]);
        }
      }
    }
  };

  // prologue
  stage_load(0);
  stage_write(0);
  __syncthreads();
  int cur = 0;
  for (int ks = 0; ks < 16; ++ks) {
    if (ks < 15) stage_load(ks + 1);       // issue early: latency under compute
    compute(cur);
    if (ks < 15) stage_write(cur ^ 1);     // other buffer: no WAR hazard
    __syncthreads();                       // single barrier per K-step
    cur ^= 1;
  }

  // Epilogue: value = Out[m0 + 16w + 4lg + r][(2ng+jt)*16 + lc]
  const int tb_abs = mt * 4 + w;
  const int b  = tb_abs >> 7;
  const int tb = tb_abs & 127;
  #pragma unroll
  for (int j = 0; j < 6; ++j) {
    const int mat = j >> 1;
    const int jt  = j & 1;
    const int tt  = 2 * ng + jt;
    #pragma unroll
    for (int r = 0; r < 4; ++r) {
      const float val = acc[j][r];
      if (mat < 2) {
        const u16 hvv = f2bu(val);
        const u16 lvv = f2bu(val - bu2f(hvv));
        const int lane_c = 4 * lg + r + 16 * (lc >> 2);
        const int hs = tt >> 1;
        const int e  = (lc & 3) + 4 * (tt & 1);
        u16* dst = ((mat == 0) ? qpk : kpk) +
                   (((size_t)(b * 128 + tb) * 4 + hs) * 2 * 64 + lane_c) * 8 + e;
        dst[0]   = hvv;
        dst[512] = lvv;
      } else {
        const int kt = tb >> 1;
        const int lane_c = lc + 16 * lg;
        const int e = r + 4 * (tb & 1);
        vpk[(((size_t)(b * 64 + kt) * 8 + tt) * 64 + lane_c) * 8 + e] = f2bu(val);
      }
    }
  }
}

// ---------------------------------------------------------------------------
// Kernel 2: causal flash attention (round-4 structure + setprio on MFMA
// clusters). 8 waves, intra-block split-K (kb = w mod 8), 1 q-tile/wave.
// Swapped QK^T so P lands in PV's A-operand layout. LDS combine (bf16).
// ---------------------------------------------------------------------------
__global__ __launch_bounds__(512, 4) void attn_kernel(
    const u16* __restrict__ qpk, const u16* __restrict__ kpk,
    const u16* __restrict__ vpk, float* __restrict__ out) {
  __shared__ float lm[8][16];
  __shared__ float ll[8][16];
  __shared__ u16 lo[8][16][132];     // bf16 partial O

  const int bid = blockIdx.x;
  const int b   = bid & 7;           // batch -> XCD affinity
  const int qt  = bid >> 3;          // 0..127
  const int w    = threadIdx.x >> 6;
  const int lane = threadIdx.x & 63;
  const int lg = lane >> 4, lc = lane & 15;

  // Q fragments: [b][qt][hs][hl][lane][8], tile stride 4096 u16
  Frag bqh[4], bql[4];
  const u16* qp = qpk + (size_t)(b * 128 + qt) * 4096 + lane * 8;
  #pragma unroll
  for (int hs = 0; hs < 4; ++hs) {
    bqh[hs].u4 = *(const u32x4*)(qp + (size_t)(hs * 2 + 0) * 512);
    bql[hs].u4 = *(const u32x4*)(qp + (size_t)(hs * 2 + 1) * 512);
  }

  f32x4 zero = {0.f, 0.f, 0.f, 0.f};
  f32x4 o_acc[8];
  #pragma unroll
  for (int i = 0; i < 8; ++i) o_acc[i] = zero;
  float m_run = -INFINITY, l_run = 0.f;

  const int myq = qt * 16 + lc;
  const int nkb = qt >> 2;           // last 64-wide k-block

  for (int kb = w; kb <= nkb; kb += 8) {
    f32x4 s[4];
    #pragma unroll
    for (int t = 0; t < 4; ++t) s[t] = zero;

    const u16* kp = kpk + (size_t)(b * 128 + kb * 4) * 4096 + lane * 8;
    __builtin_amdgcn_s_setprio(1);
    #pragma unroll
    for (int t = 0; t < 4; ++t) {
      #pragma unroll
      for (int hs = 0; hs < 4; ++hs) {
        const u16* p = kp + (size_t)(t * 8 + hs * 2) * 512;
        Frag akh, akl;
        akh.u4 = *(const u32x4*)p;
        akl.u4 = *(const u32x4*)(p + 512);
        s[t] = MFMA(akh.v, bqh[hs].v, s[t]);
        s[t] = MFMA(akh.v, bql[hs].v, s[t]);
        s[t] = MFMA(akl.v, bqh[hs].v, s[t]);
      }
    }
    __builtin_amdgcn_s_setprio(0);

    // scale by sqrt(C)=32; causal + (tril==0 -> -inf) semantics
    float pmax = -INFINITY;
    #pragma unroll
    for (int t = 0; t < 4; ++t) {
      #pragma unroll
      for (int r = 0; r < 4; ++r) {
        const int kk = kb * 64 + t * 16 + 4 * lg + r;
        float v = s[t][r] * 32.0f;
        if (kk > myq || v == 0.0f) v = -INFINITY;
        s[t][r] = v;
        pmax = fmaxf(pmax, v);
      }
    }
    pmax = fmaxf(pmax, __shfl_xor(pmax, 16));
    pmax = fmaxf(pmax, __shfl_xor(pmax, 32));
    const float m_new = fmaxf(m_run, pmax);
    const float alpha = __expf(m_run - m_new);

    float sum = 0.f;
    u16 pb[16];
    #pragma unroll
    for (int t = 0; t < 4; ++t) {
      #pragma unroll
      for (int r = 0; r < 4; ++r) {
        const float p = __expf(s[t][r] - m_new);
        sum += p;
        pb[t * 4 + r] = f2bu(p);
      }
    }
    sum += __shfl_xor(sum, 16);
    sum += __shfl_xor(sum, 32);
    l_run = l_run * alpha + sum;
    m_run = m_new;

    float al[4];
    #pragma unroll
    for (int r = 0; r < 4; ++r) al[r] = __shfl(alpha, 4 * lg + r);
    #pragma unroll
    for (int i = 0; i < 8; ++i) {
      #pragma unroll
      for (int r = 0; r < 4; ++r) o_acc[i][r] *= al[r];
    }

    Frag pa[2];
    #pragma unroll
    for (int ks = 0; ks < 2; ++ks) {
      #pragma unroll
      for (int e = 0; e < 8; ++e)
        pa[ks].s[e] = pb[(2 * ks + (e >> 2)) * 4 + (e & 3)];
    }

    __builtin_amdgcn_s_setprio(1);
    #pragma unroll
    for (int ks = 0; ks < 2; ++ks) {
      const u16* vp = vpk + (size_t)(b * 64 + kb * 2 + ks) * 4096 + lane * 8;
      #pragma unroll
      for (int ht = 0; ht < 8; ++ht) {
        Frag bv;
        bv.u4 = *(const u32x4*)(vp + (size_t)ht * 512);
        o_acc[ht] = MFMA(pa[ks].v, bv.v, o_acc[ht]);
      }
    }
    __builtin_amdgcn_s_setprio(0);
  }

  // --- combine 8 partials through LDS ---
  if (lane < 16) { lm[w][lane] = m_run; ll[w][lane] = l_run; }
  #pragma unroll
  for (int ht = 0; ht < 8; ++ht)
    #pragma unroll
    for (int r = 0; r < 4; ++r)
      lo[w][4 * lg + r][ht * 16 + lc] = f2bu(o_acc[ht][r]);
  __syncthreads();

  const int tid = threadIdx.x;
  const int q  = tid >> 5;            // 0..15
  const int hb = (tid & 31) * 4;      // 0..124
  float M = -INFINITY;
  #pragma unroll
  for (int ww = 0; ww < 8; ++ww) M = fmaxf(M, lm[ww][q]);
  float lsum = 0.f;
  f32x4 osum = {0.f, 0.f, 0.f, 0.f};
  #pragma unroll
  for (int ww = 0; ww < 8; ++ww) {
    const float sc = __expf(lm[ww][q] - M);
    lsum += sc * ll[ww][q];
    const u16x4 ov = *(const u16x4*)&lo[ww][q][hb];
    #pragma unroll
    for (int j = 0; j < 4; ++j) osum[j] += sc * bu2f(ov[j]);
  }
  const float inv = 1.0f / lsum;
  f32x4 res = {osum[0] * inv, osum[1] * inv, osum[2] * inv, osum[3] * inv};
  *(f32x4*)&out[((size_t)(b * T + qt * 16 + q)) * H + hb] = res;
}

// ---------------------------------------------------------------------------
extern "C" void kernel_launch(void* const* d_in, const int* in_sizes, int n_in,
                              void* d_out, int out_size, void* d_ws, size_t ws_size,
                              hipStream_t stream) {
  (void)in_sizes; (void)n_in; (void)out_size; (void)ws_size;
  const float* x  = (const float*)d_in[0];
  const float* Wk = (const float*)d_in[1];
  const float* Wq = (const float*)d_in[2];
  const float* Wv = (const float*)d_in[3];
  float* out = (float*)d_out;

  u16* w = (u16*)d_ws;
  const size_t WPQK = (size_t)8 * 32 * 2 * 64 * 8;       // 262144
  const size_t WPV  = (size_t)8 * 32 * 64 * 8;           // 131072
  const size_t QKP  = (size_t)NB * 128 * 4 * 2 * 64 * 8; // 4194304
  u16* wpq = w;
  u16* wpk = wpq + WPQK;
  u16* wpv = wpk + WPQK;
  u16* qpk = wpv + WPV;
  u16* kpk = qpk + QKP;
  u16* vpk = kpk + QKP;

  prep_w<<<192, 256, 0, stream>>>(Wk, Wq, Wv, wpq, wpk, wpv);
  proj_kernel<<<1024, 256, 0, stream>>>(x, wpq, wpk, wpv, qpk, kpk, vpk);
  attn_kernel<<<NB * (T / 16), 512, 0, stream>>>(qpk, kpk, vpk, out);
}